// Round 1
// baseline (522.315 us; speedup 1.0000x reference)
//
#include <hip/hip_runtime.h>

// ---------------------------------------------------------------------------
// ResNet sparse-conv block on MI355X.
// Pipeline (all on `stream`):
//   1. wprep           : W1,W2 fp32 -> bf16, transposed to [K][Cout][Cin]; zero stats
//   2. channel_stats   : per-channel sum/sumsq of x (atomics into ws)
//   3. bn_relu_bf16    : h1 = bf16(relu(bn1(x)))          [stats -> a,b in-block]
//   4. sparse_conv_mfma: out1 = sum_k gather(h1) @ W1[k]  + fused stats of out1
//   5. bn_relu_bf16    : h2 = bf16(relu(bn2(out1)))
//   6. sparse_conv_mfma: out  = sum_k gather(h2) @ W2[k] + x   (residual fused)
// ---------------------------------------------------------------------------

#define KOFF 27
#define C64  64

typedef __bf16 bf16x8 __attribute__((ext_vector_type(8)));
typedef float floatx4 __attribute__((ext_vector_type(4)));

__device__ __forceinline__ unsigned short f2bf(float x) {
    union { float f; unsigned int u; } v; v.f = x;
    unsigned int u = v.u;
    unsigned int r = u + 0x7FFFu + ((u >> 16) & 1u);   // round-to-nearest-even
    return (unsigned short)(r >> 16);
}

// --- 1. W prep: bf16 + transpose to [k][cout][cin]; block 0 zeroes stats ----
__global__ void wprep(const float* __restrict__ W1, const float* __restrict__ W2,
                      unsigned short* __restrict__ W1t, unsigned short* __restrict__ W2t,
                      float* __restrict__ stats) {
    int t = blockIdx.x * blockDim.x + threadIdx.x;
    if (blockIdx.x == 0) {           // zero 512 stat floats
        stats[threadIdx.x] = 0.f;
        stats[256 + threadIdx.x] = 0.f;
    }
    if (t >= KOFF * C64 * C64) return;
    int k = t >> 12, r = (t >> 6) & 63, c = t & 63;    // r=cout, c=cin
    W1t[t] = f2bf(W1[(k << 12) + (c << 6) + r]);
    W2t[t] = f2bf(W2[(k << 12) + (c << 6) + r]);
}

// --- 2. per-channel sum / sumsq ---------------------------------------------
__global__ void channel_stats(const float* __restrict__ in, float* __restrict__ stats,
                              int total) {
    __shared__ float s[128];
    int t = threadIdx.x;
    if (t < 128) s[t] = 0.f;
    __syncthreads();
    int i = blockIdx.x * blockDim.x + t;
    int stride = gridDim.x * blockDim.x;       // multiple of 64 -> channel fixed
    int c = i & 63;
    float s1 = 0.f, s2 = 0.f;
    for (; i < total; i += stride) {
        float v = in[i];
        s1 += v; s2 += v * v;
    }
    atomicAdd(&s[c], s1);
    atomicAdd(&s[64 + c], s2);
    __syncthreads();
    if (t < 64) {
        atomicAdd(&stats[t], s[t]);
        atomicAdd(&stats[64 + t], s[64 + t]);
    }
}

// --- 3. BN(+stats->scale/shift in-block) + ReLU + bf16 cast -----------------
__global__ void bn_relu_bf16(const float* __restrict__ in, const float* __restrict__ sums,
                             const float* __restrict__ gamma, const float* __restrict__ beta,
                             unsigned short* __restrict__ out, int total4, float invN) {
    __shared__ float sab[128];
    int t = threadIdx.x;
    if (t < 64) {
        float mu  = sums[t] * invN;
        float var = fmaxf(sums[64 + t] * invN - mu * mu, 0.f);
        float a   = gamma[t] * rsqrtf(var + 1e-5f);
        sab[t] = a;
        sab[64 + t] = beta[t] - mu * a;
    }
    __syncthreads();
    int i = blockIdx.x * blockDim.x + t;
    int stride = gridDim.x * blockDim.x;
    for (; i < total4; i += stride) {
        float4 v = ((const float4*)in)[i];
        int c0 = (i << 2) & 63;
        ushort4 o;
        o.x = f2bf(fmaxf(sab[c0]     * v.x + sab[64 + c0],     0.f));
        o.y = f2bf(fmaxf(sab[c0 + 1] * v.y + sab[64 + c0 + 1], 0.f));
        o.z = f2bf(fmaxf(sab[c0 + 2] * v.z + sab[64 + c0 + 2], 0.f));
        o.w = f2bf(fmaxf(sab[c0 + 3] * v.w + sab[64 + c0 + 3], 0.f));
        ((ushort4*)out)[i] = o;
    }
}

// --- 4/6. gather + MFMA sparse conv -----------------------------------------
// Block: 256 threads (4 waves), tile = 128 output rows x 64 cols.
// LDS A: 128 rows x 128B, chunk c of row r stored at r*128 + ((c^(r&7))<<4)
//        -> ds_*_b128 16B-aligned, <=2-way bank aliasing (free on CDNA4).
// a_frag (16x16x32): lane holds A[m=lane&15][k=(lane>>4)*8+j]
// b_frag           : lane holds B[k=(lane>>4)*8+j][n=lane&15]  (B=W[k] as cin x cout)
// C/D              : col=lane&15, row=(lane>>4)*4+reg           (m89-verified)
__global__ __launch_bounds__(256) void sparse_conv_mfma(
        const unsigned short* __restrict__ h,    // [N,64] bf16
        const int* __restrict__ idx,             // [N,27]
        const unsigned short* __restrict__ Wt,   // [27][cout=64][cin=64] bf16
        float* __restrict__ out,                 // [N,64] fp32
        const float* __restrict__ resid,         // x (conv2) or nullptr
        float* __restrict__ stats,               // sums[64],sq[64] (conv1) or nullptr
        int N) {
    __shared__ unsigned short sA[128 * 64];
    __shared__ unsigned short sW[64 * 64];
    __shared__ int   sidx[128 * KOFF];
    __shared__ float sred[128];

    int t = threadIdx.x;
    int base = blockIdx.x * 128;
    if (t < 128) sred[t] = 0.f;

    // stage this tile's neighbor indices (contiguous region -> coalesced)
    int ib = base * KOFF;
    for (int j = t; j < 128 * KOFF; j += 256) {
        int g = ib + j;
        sidx[j] = (g < N * KOFF) ? idx[g] : 0;
    }
    __syncthreads();

    int lane = t & 63, wid = t >> 6;
    int q = lane >> 4, l15 = lane & 15;
    int myc = t & 7;           // 16B chunk within a 128B row
    int row0 = t >> 3;         // rows row0 + 32*i

    floatx4 acc[2][4];
    #pragma unroll
    for (int a_ = 0; a_ < 2; ++a_)
        #pragma unroll
        for (int b_ = 0; b_ < 4; ++b_)
            acc[a_][b_] = floatx4{0.f, 0.f, 0.f, 0.f};

    #pragma unroll 1
    for (int k = 0; k < KOFF; ++k) {
        // gather: 4 chunks/thread (8 lanes cover one 128B row contiguously)
        uint4 gv[4];
        #pragma unroll
        for (int i2 = 0; i2 < 4; ++i2) {
            int row = row0 + 32 * i2;
            int gr = base + row;
            if (gr < N) {
                int g = sidx[row * KOFF + k];
                gv[i2] = *(const uint4*)(h + ((size_t)g << 6) + (myc << 3));
            } else {
                gv[i2] = make_uint4(0, 0, 0, 0);
            }
        }
        uint4 wv[2];
        #pragma unroll
        for (int i2 = 0; i2 < 2; ++i2) {
            int ch = t + 256 * i2;
            wv[i2] = *(const uint4*)(Wt + (k << 12) + (ch << 3));
        }
        __syncthreads();   // previous iteration's LDS reads complete
        #pragma unroll
        for (int i2 = 0; i2 < 4; ++i2) {
            int row = row0 + 32 * i2;
            *(uint4*)((char*)sA + row * 128 + ((myc ^ (row & 7)) << 4)) = gv[i2];
        }
        #pragma unroll
        for (int i2 = 0; i2 < 2; ++i2) {
            int ch = t + 256 * i2;
            int rw = ch >> 3, cw = ch & 7;
            *(uint4*)((char*)sW + rw * 128 + ((cw ^ (rw & 7)) << 4)) = wv[i2];
        }
        __syncthreads();   // LDS visible

        bf16x8 af[2][2], bfr[4][2];
        #pragma unroll
        for (int rt = 0; rt < 2; ++rt)
            #pragma unroll
            for (int ks = 0; ks < 2; ++ks) {
                int m = wid * 32 + rt * 16 + l15;
                int chunk = ks * 4 + q;
                af[rt][ks] = *(const bf16x8*)((const char*)sA + m * 128 + ((chunk ^ (m & 7)) << 4));
            }
        #pragma unroll
        for (int ct = 0; ct < 4; ++ct)
            #pragma unroll
            for (int ks = 0; ks < 2; ++ks) {
                int n = ct * 16 + l15;
                int chunk = ks * 4 + q;
                bfr[ct][ks] = *(const bf16x8*)((const char*)sW + n * 128 + ((chunk ^ (n & 7)) << 4));
            }
        #pragma unroll
        for (int rt = 0; rt < 2; ++rt)
            #pragma unroll
            for (int ct = 0; ct < 4; ++ct) {
                acc[rt][ct] = __builtin_amdgcn_mfma_f32_16x16x32_bf16(af[rt][0], bfr[ct][0], acc[rt][ct], 0, 0, 0);
                acc[rt][ct] = __builtin_amdgcn_mfma_f32_16x16x32_bf16(af[rt][1], bfr[ct][1], acc[rt][ct], 0, 0, 0);
            }
    }

    // epilogue: store (+ optional residual)
    #pragma unroll
    for (int rt = 0; rt < 2; ++rt) {
        int gr0 = base + wid * 32 + rt * 16 + q * 4;
        #pragma unroll
        for (int ct = 0; ct < 4; ++ct) {
            int col = ct * 16 + l15;
            #pragma unroll
            for (int r = 0; r < 4; ++r) {
                int gr = gr0 + r;
                if (gr < N) {
                    float vv = acc[rt][ct][r];
                    if (resid) vv += resid[(size_t)gr * 64 + col];
                    out[(size_t)gr * 64 + col] = vv;
                }
            }
        }
    }

    // fused per-channel stats of this conv's output (conv1 only)
    if (stats) {
        #pragma unroll
        for (int ct = 0; ct < 4; ++ct) {
            float s1 = 0.f, s2 = 0.f;
            #pragma unroll
            for (int rt = 0; rt < 2; ++rt)
                #pragma unroll
                for (int r = 0; r < 4; ++r) {
                    float vv = acc[rt][ct][r];   // invalid rows are exactly 0
                    s1 += vv; s2 += vv * vv;
                }
            s1 += __shfl_xor(s1, 16); s2 += __shfl_xor(s2, 16);
            s1 += __shfl_xor(s1, 32); s2 += __shfl_xor(s2, 32);
            if (q == 0) {
                atomicAdd(&sred[ct * 16 + l15], s1);
                atomicAdd(&sred[64 + ct * 16 + l15], s2);
            }
        }
        __syncthreads();
        if (t < 64) {
            atomicAdd(&stats[t], sred[t]);
            atomicAdd(&stats[64 + t], sred[64 + t]);
        }
    }
}

// ---------------------------------------------------------------------------
extern "C" void kernel_launch(void* const* d_in, const int* in_sizes, int n_in,
                              void* d_out, int out_size, void* d_ws, size_t ws_size,
                              hipStream_t stream) {
    const float* x      = (const float*)d_in[0];
    const int*   nbr    = (const int*)  d_in[1];
    const float* W1     = (const float*)d_in[2];
    const float* gamma1 = (const float*)d_in[3];
    const float* beta1  = (const float*)d_in[4];
    const float* W2     = (const float*)d_in[5];
    const float* gamma2 = (const float*)d_in[6];
    const float* beta2  = (const float*)d_in[7];
    float* out = (float*)d_out;

    int N = in_sizes[0] / 64;
    int total  = N * 64;
    int total4 = N * 16;
    float invN = 1.0f / (float)N;

    // workspace layout
    char* ws = (char*)d_ws;
    float*          stats = (float*)ws;                               // 512 floats
    unsigned short* W1t   = (unsigned short*)(ws + 4096);             // 27*64*64 bf16
    unsigned short* W2t   = W1t + KOFF * C64 * C64;
    unsigned short* hbuf  = (unsigned short*)(ws + 4096 + 2 * KOFF * C64 * C64 * 2);
    float*          out1  = (float*)((char*)hbuf + (size_t)N * C64 * 2);

    int convBlocks = (N + 127) / 128;

    wprep<<<432, 256, 0, stream>>>(W1, W2, W1t, W2t, stats);
    channel_stats<<<640, 256, 0, stream>>>(x, stats, total);
    bn_relu_bf16<<<1024, 256, 0, stream>>>(x, stats, gamma1, beta1, hbuf, total4, invN);
    sparse_conv_mfma<<<convBlocks, 256, 0, stream>>>(hbuf, nbr, W1t, out1, nullptr, stats + 256, N);
    bn_relu_bf16<<<1024, 256, 0, stream>>>(out1, stats + 256, gamma2, beta2, hbuf, total4, invN);
    sparse_conv_mfma<<<convBlocks, 256, 0, stream>>>(hbuf, nbr, W2t, out, x, nullptr, N);
}